// Round 20
// baseline (640.834 us; speedup 1.0000x reference)
//
#include <hip/hip_runtime.h>
#include <math.h>

#define TS 12
#define HEADS 8
#define DH 8
#define DD 64
#define BB 16
#define NN 325
#define BN (BB*NN)               // 5200
#define TOT (TS*BN*DD)           // 3,993,600
#define ROWS_FC (BB*TS*NN)       // 62,400
#define NPAD 336                 // 21 tiles of 16
#define NT 21
#define CHUNK 39                 // pairs per chunk (78 = 2*39)
#define QROWS 80                 // rows per qkv_gemm block
#define PLSTR (BB*HEADS*NN*8)    // ocat pair stride (f16 elems)
constexpr float EPS_ = 1e-5f;
constexpr float SCALE_ = 0.35355339059327373f;   // 1/sqrt(8)
constexpr float LOG2E_ = 1.4426950408889634f;

typedef _Float16 f16x4 __attribute__((ext_vector_type(4)));
typedef _Float16 f16x2 __attribute__((ext_vector_type(2)));
typedef _Float16 f16x8 __attribute__((ext_vector_type(8)));
typedef float    f32x4 __attribute__((ext_vector_type(4)));

// ---------------- K1: QKV GEMM (80 rows/block) + fused BN-stat partials ----------------
__global__ __launch_bounds__(256, 2) void qkv_gemm(
    const float* __restrict__ X, const float* __restrict__ STE,
    const float* __restrict__ Wqkv, const float* __restrict__ bqkv,
    float* __restrict__ Y, float* __restrict__ qsum, float* __restrict__ qsumsq)
{
    __shared__ float Wl[128*64];        // 32 KB
    __shared__ float Xl[QROWS][132];    // 41.25 KB (reused as stat scratch)
    int t = blockIdx.y;
    int tid = threadIdx.x;
    int r0 = blockIdx.x * QROWS;
    for (int i = tid; i < 2048; i += 256)
        ((float4*)Wl)[i] = ((const float4*)Wqkv)[i];
    for (int i = tid; i < QROWS*32; i += 256) {
        int row = i >> 5, q = i & 31;
        int r = r0 + row;
        int b = r / NN, n = r % NN;
        size_t src = (((size_t)b*TS + t)*NN + n)*DD;
        float4 v = (q < 16) ? ((const float4*)(X + src))[q]
                            : ((const float4*)(STE + src))[q-16];
        *(float4*)&Xl[row][q*4] = v;
    }
    __syncthreads();
    int cg = tid & 15, rg = tid >> 4;
    int c0 = cg*4;
    float4 a[5] = {};
    #pragma unroll 4
    for (int k4 = 0; k4 < 32; ++k4) {
        float4 w0 = *(const float4*)&Wl[(4*k4+0)*64 + c0];
        float4 w1 = *(const float4*)&Wl[(4*k4+1)*64 + c0];
        float4 w2 = *(const float4*)&Wl[(4*k4+2)*64 + c0];
        float4 w3 = *(const float4*)&Wl[(4*k4+3)*64 + c0];
        #pragma unroll
        for (int i = 0; i < 5; ++i) {
            float4 xv = *(const float4*)&Xl[rg*5 + i][k4*4];
            a[i].x += xv.x*w0.x + xv.y*w1.x + xv.z*w2.x + xv.w*w3.x;
            a[i].y += xv.x*w0.y + xv.y*w1.y + xv.z*w2.y + xv.w*w3.y;
            a[i].z += xv.x*w0.z + xv.y*w1.z + xv.z*w2.z + xv.w*w3.z;
            a[i].w += xv.x*w0.w + xv.y*w1.w + xv.z*w2.w + xv.w*w3.w;
        }
    }
    float4 bq = *(const float4*)(bqkv + c0);
    float4 ps = make_float4(0.f,0.f,0.f,0.f), pq = ps;
    #pragma unroll
    for (int i = 0; i < 5; ++i) {
        int r = r0 + rg*5 + i;
        float4 o;
        o.x = a[i].x + bq.x; o.y = a[i].y + bq.y;
        o.z = a[i].z + bq.z; o.w = a[i].w + bq.w;
        *(float4*)&Y[((size_t)t*BN + r)*64 + c0] = o;
        ps.x += o.x; ps.y += o.y; ps.z += o.z; ps.w += o.w;
        pq.x += o.x*o.x; pq.y += o.y*o.y; pq.z += o.z*o.z; pq.w += o.w*o.w;
    }
    float* red = (float*)Xl;
    __syncthreads();
    *(float4*)&red[rg*64 + c0] = ps;
    *(float4*)&red[1024 + rg*64 + c0] = pq;
    __syncthreads();
    if (tid < 64) {
        float s = 0.f, q = 0.f;
        #pragma unroll
        for (int r = 0; r < 16; ++r) { s += red[r*64 + tid]; q += red[1024 + r*64 + tid]; }
        atomicAdd(&qsum[t*64 + tid], s);
        atomicAdd(&qsumsq[t*64 + tid], q);
    }
}

// ---------------- K2: column reduce (sum, sumsq) over [t][R][64] ----------------
__global__ __launch_bounds__(256) void col_reduce(
    const float* __restrict__ src, float* __restrict__ osum, float* __restrict__ osumsq,
    int R, int chunkrows)
{
    __shared__ float red[256];
    int t = blockIdx.y;
    int tid = threadIdx.x;
    int c = tid & 63, rl = tid >> 6;
    int r0 = blockIdx.x * chunkrows;
    int r1 = r0 + chunkrows;
    float s = 0.f, s2 = 0.f;
    for (int r = r0 + rl; r < r1; r += 4) {
        float v = src[((size_t)t*R + r)*64 + c];
        s += v; s2 += v*v;
    }
    red[tid] = s; __syncthreads();
    if (tid < 64) atomicAdd(&osum[t*64 + tid], red[tid] + red[tid+64] + red[tid+128] + red[tid+192]);
    __syncthreads();
    red[tid] = s2; __syncthreads();
    if (tid < 64) atomicAdd(&osumsq[t*64 + tid], red[tid] + red[tid+64] + red[tid+128] + red[tid+192]);
}

// ---------------- K3: finalize QKV BN stats ----------------
__global__ void qkv_stats(const float* __restrict__ qsum, const float* __restrict__ qsumsq,
                          const float* __restrict__ g, const float* __restrict__ be,
                          float* __restrict__ qsc, float* __restrict__ qsh)
{
    int i = blockIdx.x * blockDim.x + threadIdx.x;
    if (i >= TS*64) return;
    int c = i & 63;
    float mean = qsum[i] * (1.0f / BN);
    float var  = qsumsq[i] * (1.0f / BN) - mean*mean;
    float sc = g[c] * rsqrtf(var + EPS_);
    qsc[i] = sc;
    qsh[i] = be[c] - mean * sc;
}

// ---------------- K4: BN+ReLU + relayout to f16 [t][b][h][n][8] ----------------
__global__ __launch_bounds__(256) void bn_relayout_h(
    const float* __restrict__ Y, const float* __restrict__ qsc, const float* __restrict__ qsh,
    _Float16* __restrict__ qkvh)
{
    size_t idx = (size_t)blockIdx.x * 256 + threadIdx.x;
    if (idx >= TOT) return;
    int c = (int)(idx & 63);
    size_t tr = idx >> 6;
    int t = (int)(tr / BN);
    int r = (int)(tr % BN);
    float v = fmaxf(Y[idx] * qsc[t*64 + c] + qsh[t*64 + c], 0.0f);
    int b = r / NN, n = r % NN, h = c >> 3, d = c & 7;
    qkvh[((((size_t)t*BB + b)*HEADS + h)*NN + n)*DH + d] = (_Float16)v;
}

// ---------------- K4b: combined weights Wcomb[s] = lin_w[s] @ W_fc ----------------
__global__ __launch_bounds__(256) void wcomb_k(
    const float* __restrict__ lin_w, const float* __restrict__ Wfc,
    float* __restrict__ wcomb)
{
    __shared__ float Wl[64*64];
    int s = blockIdx.y, kt = blockIdx.x;
    int tid = threadIdx.x;
    int c = tid & 63, rl = tid >> 6;
    for (int i = tid; i < 1024; i += 256)
        ((float4*)Wl)[i] = ((const float4*)Wfc)[i];
    __syncthreads();
    #pragma unroll
    for (int i = 0; i < 4; ++i) {
        int k = kt*16 + rl*4 + i;
        const float* lw = lin_w + ((size_t)s*768 + k)*64;
        float a = 0.f;
        #pragma unroll
        for (int m4 = 0; m4 < 16; ++m4) {
            float4 lv = *(const float4*)(lw + m4*4);
            a += lv.x*Wl[(4*m4+0)*64+c] + lv.y*Wl[(4*m4+1)*64+c]
               + lv.z*Wl[(4*m4+2)*64+c] + lv.w*Wl[(4*m4+3)*64+c];
        }
        wcomb[((size_t)s*768 + k)*64 + c] = a;
    }
}

// ---------------- K4c: bcomb[s] = lin_b[s] @ W_fc + b_fc ----------------
__global__ void bcomb_k(const float* __restrict__ lin_b, const float* __restrict__ Wfc,
                        const float* __restrict__ bfc, float* __restrict__ bcomb)
{
    int i = blockIdx.x * 256 + threadIdx.x;
    if (i >= TS*64) return;
    int s = i >> 6, c = i & 63;
    float a = bfc[c];
    for (int m = 0; m < 64; ++m) a += lin_b[s*64 + m] * Wfc[m*64 + c];
    bcomb[i] = a;
}

// ---------------- K4d: y_init — seed y with bcomb[s] ----------------
__global__ __launch_bounds__(256) void y_init(
    float* __restrict__ y, const float* __restrict__ bcomb)
{
    size_t idx = (size_t)blockIdx.x * 256 + threadIdx.x;
    if (idx >= TOT) return;
    int c = (int)(idx & 63);
    size_t row = idx >> 6;
    int s = (int)((row / NN) % TS);
    y[idx] = bcomb[s*64 + c];
}

// ---------------- K5: MFMA attention, two-pass recompute (zero S storage) ----------------
// R20: S array deleted. R18/R19 showed the S group parks in AGPRs and every
// fmax/sub read pays a v_accvgpr shuttle (~8/tile vs ~14 useful VALU). Pass 1
// recomputes nothing-stored QK MFMAs folding straight into the running max
// (exact max -> no online rescale, one shfl pair per strip); pass 2 recomputes
// the QK MFMA per tile and does exp+PV. +21 MFMA/strip (MfmaUtil 24->~36%, not
// the bottleneck) buys removal of all shuttle VALU + rescale machinery.
__global__ __launch_bounds__(256, 4) void attn_ocat(
    const _Float16* __restrict__ qkvh, _Float16* __restrict__ ocat, int p0)
{
    int pl = blockIdx.x, b = blockIdx.y, h = blockIdx.z;
    int p = p0 + pl;
    int s = 0, base = 0;
    while (base + s + 1 <= p) { base += s + 1; ++s; }
    int j = p - base;

    __shared__ _Float16 Kl[NPAD*8];          // [m][k], rows m>=325 zero
    __shared__ _Float16 VT[16][NPAD+8];      // [d][m], d 9..15 zero, d=8 ones

    int tid  = threadIdx.x;
    int lane = tid & 63, wv = tid >> 6;
    int lq = lane >> 4, lr = lane & 15;

    for (int i = tid; i < (NPAD*8)/2; i += 256) ((unsigned*)Kl)[i] = 0u;
    for (int i = tid; i < (16*(NPAD+8))/2; i += 256) ((unsigned*)(&VT[0][0]))[i] = 0u;
    __syncthreads();
    const _Float16* kvsrc = qkvh + (((size_t)j*BB + b)*HEADS + h)*(NN*DH);
    for (int i = tid; i < (NN*DH)/2; i += 256) ((unsigned*)Kl)[i] = ((const unsigned*)kvsrc)[i];
    for (int i = tid; i < NN*DH; i += 256) { int m = i >> 3, d = i & 7; VT[d][m] = kvsrc[i]; }
    for (int i = tid; i < NPAD; i += 256) VT[8][i] = (_Float16)1.0f;   // den row
    __syncthreads();

    const _Float16* qh = qkvh + (((size_t)s*BB + b)*HEADS + h)*(NN*DH);
    _Float16* obase = ocat + (((size_t)(pl*BB + b)*HEADS + h)*NN)*8;

    for (int st = wv; st < NT; st += 4) {
        int n0 = st * 16;
        f16x4 qf = {0,0,0,0};
        int nq = n0 + lr;
        if (lq < 2 && nq < NN) qf = *(const f16x4*)(qh + nq*DH + lq*4);
        qf *= (_Float16)(SCALE_ * LOG2E_);   // log2-domain scores

        // pass 1: exact row max; S transient (4 regs at a time, no storage)
        float mx = 0.f;                      // S >= 0 (ReLU'd Q,K); pads give 0
        #pragma unroll
        for (int mt = 0; mt < NT; ++mt) {
            f16x4 kf = {0,0,0,0};
            if (lq < 2) kf = *(const f16x4*)(&Kl[(mt*16 + lr)*8 + lq*4]);
            f32x4 sA = __builtin_amdgcn_mfma_f32_16x16x16f16(kf, qf, (f32x4){0.f,0.f,0.f,0.f}, 0, 0, 0);
            mx = fmaxf(mx, fmaxf(fmaxf(sA[0], sA[1]), fmaxf(sA[2], sA[3])));
        }
        mx = fmaxf(mx, __shfl_xor(mx, 16));
        mx = fmaxf(mx, __shfl_xor(mx, 32));

        // pass 2: recompute S, P = 2^(S-mx), O^T = V^T.P^T (den row inside)
        f32x4 ot = {0.f, 0.f, 0.f, 0.f};
        #pragma unroll
        for (int mt = 0; mt < NT; ++mt) {
            f16x4 kf = {0,0,0,0};
            if (lq < 2) kf = *(const f16x4*)(&Kl[(mt*16 + lr)*8 + lq*4]);
            f32x4 sA = __builtin_amdgcn_mfma_f32_16x16x16f16(kf, qf, (f32x4){0.f,0.f,0.f,0.f}, 0, 0, 0);
            float e0 = __builtin_amdgcn_exp2f(sA[0] - mx);
            float e1 = __builtin_amdgcn_exp2f(sA[1] - mx);
            float e2 = __builtin_amdgcn_exp2f(sA[2] - mx);
            float e3 = __builtin_amdgcn_exp2f(sA[3] - mx);
            if (mt == NT-1) {                 // only tile 20 has pad rows
                if (lq*4 + 0 >= 5) e0 = 0.f;
                if (lq*4 + 1 >= 5) e1 = 0.f;
                if (lq*4 + 2 >= 5) e2 = 0.f;
                if (lq*4 + 3 >= 5) e3 = 0.f;
            }
            f16x2 plo = __builtin_bit_cast(f16x2, __builtin_amdgcn_cvt_pkrtz(e0, e1));
            f16x2 phi = __builtin_bit_cast(f16x2, __builtin_amdgcn_cvt_pkrtz(e2, e3));
            f16x4 pf = {plo.x, plo.y, phi.x, phi.y};
            f16x4 vf = *(const f16x4*)(&VT[lr][mt*16 + lq*4]);
            ot = __builtin_amdgcn_mfma_f32_16x16x16f16(vf, pf, ot, 0, 0, 0);
        }
        float den = __shfl(ot[0], 32 + lr);   // C row 8 lives in lanes 32..47
        float inv = __builtin_amdgcn_rcpf(den);

        if (lq < 2 && nq < NN) {
            f16x2 a01 = __builtin_bit_cast(f16x2, __builtin_amdgcn_cvt_pkrtz(ot[0]*inv, ot[1]*inv));
            f16x2 a23 = __builtin_bit_cast(f16x2, __builtin_amdgcn_cvt_pkrtz(ot[2]*inv, ot[3]*inv));
            f16x4 o4 = {a01.x, a01.y, a23.x, a23.y};
            *(f16x4*)(obase + (size_t)nq*8 + lq*4) = o4;
        }
    }
}

// ---------------- K6: y_accum — 80 rows/block: wcomb staged once per block ----------------
// R20: grid (65, CHUNK) instead of (325, CHUNK): wcomb re-staging drops 5x
// (203 MB -> 40 MB of L2 refetch), 20 row-iters/thread for latency hiding.
__global__ __launch_bounds__(256) void y_accum(
    const _Float16* __restrict__ ocat, const float* __restrict__ wcomb,
    float* y, int p0)
{
    int rt = blockIdx.x, pl = blockIdx.y;
    int p = p0 + pl;
    int s = 0, base = 0;
    while (base + s + 1 <= p) { base += s + 1; ++s; }
    int jj = p - base;

    __shared__ float Wl[64*64];
    int tid = threadIdx.x;
    const float4* wsrc = (const float4*)(wcomb + ((size_t)s*768 + jj*64)*64);
    for (int i = tid; i < 1024; i += 256) ((float4*)Wl)[i] = wsrc[i];
    __syncthreads();

    int c = tid & 63, rl = tid >> 6;
    const _Float16* ob = ocat + (size_t)pl*PLSTR;
    #pragma unroll 4
    for (int it = 0; it < 20; ++it) {
        int r = rt*80 + it*4 + rl;
        int b = r / NN, n = r % NN;
        const _Float16* orow = ob + ((size_t)b*HEADS*NN + n)*8;
        float a = 0.f;
        #pragma unroll
        for (int h = 0; h < 8; ++h) {
            f16x8 v = *(const f16x8*)(orow + (size_t)h*NN*8);
            a += (float)v[0]*Wl[(h*8+0)*64+c] + (float)v[1]*Wl[(h*8+1)*64+c]
               + (float)v[2]*Wl[(h*8+2)*64+c] + (float)v[3]*Wl[(h*8+3)*64+c]
               + (float)v[4]*Wl[(h*8+4)*64+c] + (float)v[5]*Wl[(h*8+5)*64+c]
               + (float)v[6]*Wl[(h*8+6)*64+c] + (float)v[7]*Wl[(h*8+7)*64+c];
        }
        atomicAdd(&y[((size_t)(b*TS + s)*NN + n)*64 + c], a);
    }
}

// ---------------- K8: finalize fc BN stats ----------------
__global__ void fc_stats(const float* __restrict__ fsum, const float* __restrict__ fsumsq,
                         const float* __restrict__ g, const float* __restrict__ be,
                         float* __restrict__ fsc, float* __restrict__ fsh)
{
    int c = threadIdx.x;
    if (c >= 64) return;
    float mean = fsum[c] * (1.0f / ROWS_FC);
    float var  = fsumsq[c] * (1.0f / ROWS_FC) - mean*mean;
    float sc = g[c] * rsqrtf(var + EPS_);
    fsc[c] = sc;
    fsh[c] = be[c] - mean * sc;
}

// ---------------- K9: final BN+ReLU in place on d_out ----------------
__global__ __launch_bounds__(256) void bn_out(
    float* __restrict__ out, const float* __restrict__ fsc, const float* __restrict__ fsh)
{
    size_t idx = (size_t)blockIdx.x * 256 + threadIdx.x;
    if (idx >= TOT) return;
    int c = (int)(idx & 63);
    out[idx] = fmaxf(out[idx] * fsc[c] + fsh[c], 0.0f);
}

extern "C" void kernel_launch(void* const* d_in, const int* in_sizes, int n_in,
                              void* d_out, int out_size, void* d_ws, size_t ws_size,
                              hipStream_t stream)
{
    const float* X     = (const float*)d_in[0];
    const float* STE   = (const float*)d_in[1];
    const float* Wqkv  = (const float*)d_in[2];
    const float* bqkv  = (const float*)d_in[3];
    const float* gqkv  = (const float*)d_in[4];
    const float* beqkv = (const float*)d_in[5];
    const float* lin_w = (const float*)d_in[6];
    const float* lin_b = (const float*)d_in[7];
    const float* Wfc   = (const float*)d_in[8];
    const float* bfc   = (const float*)d_in[9];
    const float* gfc   = (const float*)d_in[10];
    const float* befc  = (const float*)d_in[11];

    // ws layout (f32 units):
    // [qkvh: TOT/2][st: 4096][wcomb: 12*768*64][bcomb: 768][ocat(f16): CHUNK*PLSTR/2]
    float* ws    = (float*)d_ws;
    _Float16* qkvh = (_Float16*)ws;
    float* st    = ws + (size_t)TOT/2;
    float* wcomb = st + 4096;
    float* bcomb = wcomb + (size_t)TS*768*64;
    _Float16* ocat = (_Float16*)(bcomb + 768);
    float* Y     = (float*)ocat;
    float* y     = (float*)d_out;          // y accumulates in d_out; BN in place

    float* qsum   = st;            // 768
    float* qsumsq = st + 768;      // 768
    float* fsum   = st + 1536;     // 64
    float* fsumsq = st + 1600;     // 64  -> first 1664 floats zeroed each call
    float* qsc    = st + 1664;     // 768
    float* qsh    = st + 2432;     // 768
    float* fsc    = st + 3200;     // 64
    float* fsh    = st + 3264;     // 64

    hipMemsetAsync(st, 0, 1664 * sizeof(float), stream);

    qkv_gemm<<<dim3(BN/QROWS, TS), 256, 0, stream>>>(X, STE, Wqkv, bqkv, Y, qsum, qsumsq);
    qkv_stats<<<3, 256, 0, stream>>>(qsum, qsumsq, gqkv, beqkv, qsc, qsh);
    bn_relayout_h<<<TOT/256, 256, 0, stream>>>(Y, qsc, qsh, qkvh);
    wcomb_k<<<dim3(48, TS), 256, 0, stream>>>(lin_w, Wfc, wcomb);
    bcomb_k<<<3, 256, 0, stream>>>(lin_b, Wfc, bfc, bcomb);
    y_init<<<TOT/256, 256, 0, stream>>>(y, bcomb);

    for (int ch = 0; ch < 2; ++ch) {
        int p0 = ch * CHUNK;
        attn_ocat<<<dim3(CHUNK, BB, HEADS), 256, 0, stream>>>(qkvh, ocat, p0);
        y_accum<<<dim3(65, CHUNK), 256, 0, stream>>>(ocat, wcomb, y, p0);
    }

    col_reduce<<<dim3(96, 1), 256, 0, stream>>>(y, fsum, fsumsq, ROWS_FC, ROWS_FC/96);
    fc_stats<<<1, 64, 0, stream>>>(fsum, fsumsq, gfc, befc, fsc, fsh);
    bn_out<<<TOT/256, 256, 0, stream>>>(y, fsc, fsh);
}

// Round 21
// 460.666 us; speedup vs baseline: 1.3911x; 1.3911x over previous
//
#include <hip/hip_runtime.h>
#include <math.h>

#define TS 12
#define HEADS 8
#define DH 8
#define DD 64
#define BB 16
#define NN 325
#define BN (BB*NN)               // 5200
#define TOT (TS*BN*DD)           // 3,993,600
#define ROWS_FC (BB*TS*NN)       // 62,400
#define NPAD 336                 // 21 tiles of 16
#define NT 21
#define CHUNK 39                 // pairs per chunk (78 = 2*39)
#define QROWS 80                 // rows per qkv_gemm block
#define PLSTR (BB*HEADS*NN*8)    // ocat pair stride (f16 elems)
constexpr float EPS_ = 1e-5f;
constexpr float SCALE_ = 0.35355339059327373f;   // 1/sqrt(8)
constexpr float LOG2E_ = 1.4426950408889634f;

typedef _Float16 f16x4 __attribute__((ext_vector_type(4)));
typedef _Float16 f16x2 __attribute__((ext_vector_type(2)));
typedef _Float16 f16x8 __attribute__((ext_vector_type(8)));
typedef float    f32x4 __attribute__((ext_vector_type(4)));

// ---------------- K1: QKV GEMM (80 rows/block) + fused BN-stat partials ----------------
__global__ __launch_bounds__(256, 2) void qkv_gemm(
    const float* __restrict__ X, const float* __restrict__ STE,
    const float* __restrict__ Wqkv, const float* __restrict__ bqkv,
    float* __restrict__ Y, float* __restrict__ qsum, float* __restrict__ qsumsq)
{
    __shared__ float Wl[128*64];        // 32 KB
    __shared__ float Xl[QROWS][132];    // 41.25 KB (reused as stat scratch)
    int t = blockIdx.y;
    int tid = threadIdx.x;
    int r0 = blockIdx.x * QROWS;
    for (int i = tid; i < 2048; i += 256)
        ((float4*)Wl)[i] = ((const float4*)Wqkv)[i];
    for (int i = tid; i < QROWS*32; i += 256) {
        int row = i >> 5, q = i & 31;
        int r = r0 + row;
        int b = r / NN, n = r % NN;
        size_t src = (((size_t)b*TS + t)*NN + n)*DD;
        float4 v = (q < 16) ? ((const float4*)(X + src))[q]
                            : ((const float4*)(STE + src))[q-16];
        *(float4*)&Xl[row][q*4] = v;
    }
    __syncthreads();
    int cg = tid & 15, rg = tid >> 4;
    int c0 = cg*4;
    float4 a[5] = {};
    #pragma unroll 4
    for (int k4 = 0; k4 < 32; ++k4) {
        float4 w0 = *(const float4*)&Wl[(4*k4+0)*64 + c0];
        float4 w1 = *(const float4*)&Wl[(4*k4+1)*64 + c0];
        float4 w2 = *(const float4*)&Wl[(4*k4+2)*64 + c0];
        float4 w3 = *(const float4*)&Wl[(4*k4+3)*64 + c0];
        #pragma unroll
        for (int i = 0; i < 5; ++i) {
            float4 xv = *(const float4*)&Xl[rg*5 + i][k4*4];
            a[i].x += xv.x*w0.x + xv.y*w1.x + xv.z*w2.x + xv.w*w3.x;
            a[i].y += xv.x*w0.y + xv.y*w1.y + xv.z*w2.y + xv.w*w3.y;
            a[i].z += xv.x*w0.z + xv.y*w1.z + xv.z*w2.z + xv.w*w3.z;
            a[i].w += xv.x*w0.w + xv.y*w1.w + xv.z*w2.w + xv.w*w3.w;
        }
    }
    float4 bq = *(const float4*)(bqkv + c0);
    float4 ps = make_float4(0.f,0.f,0.f,0.f), pq = ps;
    #pragma unroll
    for (int i = 0; i < 5; ++i) {
        int r = r0 + rg*5 + i;
        float4 o;
        o.x = a[i].x + bq.x; o.y = a[i].y + bq.y;
        o.z = a[i].z + bq.z; o.w = a[i].w + bq.w;
        *(float4*)&Y[((size_t)t*BN + r)*64 + c0] = o;
        ps.x += o.x; ps.y += o.y; ps.z += o.z; ps.w += o.w;
        pq.x += o.x*o.x; pq.y += o.y*o.y; pq.z += o.z*o.z; pq.w += o.w*o.w;
    }
    float* red = (float*)Xl;
    __syncthreads();
    *(float4*)&red[rg*64 + c0] = ps;
    *(float4*)&red[1024 + rg*64 + c0] = pq;
    __syncthreads();
    if (tid < 64) {
        float s = 0.f, q = 0.f;
        #pragma unroll
        for (int r = 0; r < 16; ++r) { s += red[r*64 + tid]; q += red[1024 + r*64 + tid]; }
        atomicAdd(&qsum[t*64 + tid], s);
        atomicAdd(&qsumsq[t*64 + tid], q);
    }
}

// ---------------- K2: column reduce (sum, sumsq) over [t][R][64] ----------------
__global__ __launch_bounds__(256) void col_reduce(
    const float* __restrict__ src, float* __restrict__ osum, float* __restrict__ osumsq,
    int R, int chunkrows)
{
    __shared__ float red[256];
    int t = blockIdx.y;
    int tid = threadIdx.x;
    int c = tid & 63, rl = tid >> 6;
    int r0 = blockIdx.x * chunkrows;
    int r1 = r0 + chunkrows;
    float s = 0.f, s2 = 0.f;
    for (int r = r0 + rl; r < r1; r += 4) {
        float v = src[((size_t)t*R + r)*64 + c];
        s += v; s2 += v*v;
    }
    red[tid] = s; __syncthreads();
    if (tid < 64) atomicAdd(&osum[t*64 + tid], red[tid] + red[tid+64] + red[tid+128] + red[tid+192]);
    __syncthreads();
    red[tid] = s2; __syncthreads();
    if (tid < 64) atomicAdd(&osumsq[t*64 + tid], red[tid] + red[tid+64] + red[tid+128] + red[tid+192]);
}

// ---------------- K3: finalize QKV BN stats ----------------
__global__ void qkv_stats(const float* __restrict__ qsum, const float* __restrict__ qsumsq,
                          const float* __restrict__ g, const float* __restrict__ be,
                          float* __restrict__ qsc, float* __restrict__ qsh)
{
    int i = blockIdx.x * blockDim.x + threadIdx.x;
    if (i >= TS*64) return;
    int c = i & 63;
    float mean = qsum[i] * (1.0f / BN);
    float var  = qsumsq[i] * (1.0f / BN) - mean*mean;
    float sc = g[c] * rsqrtf(var + EPS_);
    qsc[i] = sc;
    qsh[i] = be[c] - mean * sc;
}

// ---------------- K4: BN+ReLU + relayout to f16 [t][b][h][n][8] ----------------
__global__ __launch_bounds__(256) void bn_relayout_h(
    const float* __restrict__ Y, const float* __restrict__ qsc, const float* __restrict__ qsh,
    _Float16* __restrict__ qkvh)
{
    size_t idx = (size_t)blockIdx.x * 256 + threadIdx.x;
    if (idx >= TOT) return;
    int c = (int)(idx & 63);
    size_t tr = idx >> 6;
    int t = (int)(tr / BN);
    int r = (int)(tr % BN);
    float v = fmaxf(Y[idx] * qsc[t*64 + c] + qsh[t*64 + c], 0.0f);
    int b = r / NN, n = r % NN, h = c >> 3, d = c & 7;
    qkvh[((((size_t)t*BB + b)*HEADS + h)*NN + n)*DH + d] = (_Float16)v;
}

// ---------------- K4b: combined weights Wcomb[s] = lin_w[s] @ W_fc ----------------
__global__ __launch_bounds__(256) void wcomb_k(
    const float* __restrict__ lin_w, const float* __restrict__ Wfc,
    float* __restrict__ wcomb)
{
    __shared__ float Wl[64*64];
    int s = blockIdx.y, kt = blockIdx.x;
    int tid = threadIdx.x;
    int c = tid & 63, rl = tid >> 6;
    for (int i = tid; i < 1024; i += 256)
        ((float4*)Wl)[i] = ((const float4*)Wfc)[i];
    __syncthreads();
    #pragma unroll
    for (int i = 0; i < 4; ++i) {
        int k = kt*16 + rl*4 + i;
        const float* lw = lin_w + ((size_t)s*768 + k)*64;
        float a = 0.f;
        #pragma unroll
        for (int m4 = 0; m4 < 16; ++m4) {
            float4 lv = *(const float4*)(lw + m4*4);
            a += lv.x*Wl[(4*m4+0)*64+c] + lv.y*Wl[(4*m4+1)*64+c]
               + lv.z*Wl[(4*m4+2)*64+c] + lv.w*Wl[(4*m4+3)*64+c];
        }
        wcomb[((size_t)s*768 + k)*64 + c] = a;
    }
}

// ---------------- K4c: bcomb[s] = lin_b[s] @ W_fc + b_fc ----------------
__global__ void bcomb_k(const float* __restrict__ lin_b, const float* __restrict__ Wfc,
                        const float* __restrict__ bfc, float* __restrict__ bcomb)
{
    int i = blockIdx.x * 256 + threadIdx.x;
    if (i >= TS*64) return;
    int s = i >> 6, c = i & 63;
    float a = bfc[c];
    for (int m = 0; m < 64; ++m) a += lin_b[s*64 + m] * Wfc[m*64 + c];
    bcomb[i] = a;
}

// ---------------- K4d: y_init — seed y with bcomb[s] ----------------
__global__ __launch_bounds__(256) void y_init(
    float* __restrict__ y, const float* __restrict__ bcomb)
{
    size_t idx = (size_t)blockIdx.x * 256 + threadIdx.x;
    if (idx >= TOT) return;
    int c = (int)(idx & 63);
    size_t row = idx >> 6;
    int s = (int)((row / NN) % TS);
    y[idx] = bcomb[s*64 + c];
}

// ---------------- K5: MFMA attention, 3-group online softmax, f16 ocat ----------------
// R21: exact revert to R19 (best measured: 124us/chunk, occ 45%). R20's
// two-pass recompute regressed (VALUBusy 79->59%, WRITE 25->75MB spill
// signature); stored-S 3-group form stands.
__global__ __launch_bounds__(256, 4) void attn_ocat(
    const _Float16* __restrict__ qkvh, _Float16* __restrict__ ocat, int p0)
{
    int pl = blockIdx.x, b = blockIdx.y, h = blockIdx.z;
    int p = p0 + pl;
    int s = 0, base = 0;
    while (base + s + 1 <= p) { base += s + 1; ++s; }
    int j = p - base;

    __shared__ _Float16 Kl[NPAD*8];          // [m][k], rows m>=325 zero
    __shared__ _Float16 VT[16][NPAD+8];      // [d][m], d 9..15 zero, d=8 ones

    int tid  = threadIdx.x;
    int lane = tid & 63, wv = tid >> 6;
    int lq = lane >> 4, lr = lane & 15;

    for (int i = tid; i < (NPAD*8)/2; i += 256) ((unsigned*)Kl)[i] = 0u;
    for (int i = tid; i < (16*(NPAD+8))/2; i += 256) ((unsigned*)(&VT[0][0]))[i] = 0u;
    __syncthreads();
    const _Float16* kvsrc = qkvh + (((size_t)j*BB + b)*HEADS + h)*(NN*DH);
    for (int i = tid; i < (NN*DH)/2; i += 256) ((unsigned*)Kl)[i] = ((const unsigned*)kvsrc)[i];
    for (int i = tid; i < NN*DH; i += 256) { int m = i >> 3, d = i & 7; VT[d][m] = kvsrc[i]; }
    for (int i = tid; i < NPAD; i += 256) VT[8][i] = (_Float16)1.0f;   // den row
    __syncthreads();

    const _Float16* qh = qkvh + (((size_t)s*BB + b)*HEADS + h)*(NN*DH);
    _Float16* obase = ocat + (((size_t)(pl*BB + b)*HEADS + h)*NN)*8;

    for (int st = wv; st < NT; st += 4) {
        int n0 = st * 16;
        f16x4 qf = {0,0,0,0};
        int nq = n0 + lr;
        if (lq < 2 && nq < NN) qf = *(const f16x4*)(qh + nq*DH + lq*4);
        qf *= (_Float16)(SCALE_ * LOG2E_);   // log2-domain scores

        f32x4 ot = {0.f, 0.f, 0.f, 0.f};
        float mx = 0.f;                      // S >= 0 always (ReLU'd Q,K)
        #pragma unroll
        for (int g = 0; g < 3; ++g) {
            const int mt0 = g * 7;
            const int mt1 = mt0 + 7;
            f32x4 S[7];
            float gmx = 0.f;
            #pragma unroll
            for (int mt = mt0; mt < mt1; ++mt) {
                f16x4 kf = {0,0,0,0};
                if (lq < 2) kf = *(const f16x4*)(&Kl[(mt*16 + lr)*8 + lq*4]);
                S[mt-mt0] = __builtin_amdgcn_mfma_f32_16x16x16f16(kf, qf, (f32x4){0.f,0.f,0.f,0.f}, 0, 0, 0);
                gmx = fmaxf(gmx, fmaxf(fmaxf(S[mt-mt0][0], S[mt-mt0][1]),
                                       fmaxf(S[mt-mt0][2], S[mt-mt0][3])));
            }
            gmx = fmaxf(gmx, __shfl_xor(gmx, 16));
            gmx = fmaxf(gmx, __shfl_xor(gmx, 32));
            float nmx = fmaxf(mx, gmx);
            ot *= __builtin_amdgcn_exp2f(mx - nmx);   // rescale prior acc (den row too)
            mx = nmx;
            #pragma unroll
            for (int mt = mt0; mt < mt1; ++mt) {
                float e0 = __builtin_amdgcn_exp2f(S[mt-mt0][0] - mx);
                float e1 = __builtin_amdgcn_exp2f(S[mt-mt0][1] - mx);
                float e2 = __builtin_amdgcn_exp2f(S[mt-mt0][2] - mx);
                float e3 = __builtin_amdgcn_exp2f(S[mt-mt0][3] - mx);
                if (mt == NT-1) {                 // only tile 20 has pad rows
                    if (lq*4 + 0 >= 5) e0 = 0.f;
                    if (lq*4 + 1 >= 5) e1 = 0.f;
                    if (lq*4 + 2 >= 5) e2 = 0.f;
                    if (lq*4 + 3 >= 5) e3 = 0.f;
                }
                f16x2 plo = __builtin_bit_cast(f16x2, __builtin_amdgcn_cvt_pkrtz(e0, e1));
                f16x2 phi = __builtin_bit_cast(f16x2, __builtin_amdgcn_cvt_pkrtz(e2, e3));
                f16x4 pf = {plo.x, plo.y, phi.x, phi.y};
                f16x4 vf = *(const f16x4*)(&VT[lr][mt*16 + lq*4]);
                ot = __builtin_amdgcn_mfma_f32_16x16x16f16(vf, pf, ot, 0, 0, 0);
            }
        }
        float den = __shfl(ot[0], 32 + lr);   // C row 8 lives in lanes 32..47
        float inv = __builtin_amdgcn_rcpf(den);

        if (lq < 2 && nq < NN) {
            f16x2 a01 = __builtin_bit_cast(f16x2, __builtin_amdgcn_cvt_pkrtz(ot[0]*inv, ot[1]*inv));
            f16x2 a23 = __builtin_bit_cast(f16x2, __builtin_amdgcn_cvt_pkrtz(ot[2]*inv, ot[3]*inv));
            f16x4 o4 = {a01.x, a01.y, a23.x, a23.y};
            *(f16x4*)(obase + (size_t)nq*8 + lq*4) = o4;
        }
    }
}

// ---------------- K6: y_accum — one block per (rowtile, pair), rank-64 update ----------------
__global__ __launch_bounds__(256) void y_accum(
    const _Float16* __restrict__ ocat, const float* __restrict__ wcomb,
    float* y, int p0)
{
    int rt = blockIdx.x, pl = blockIdx.y;
    int p = p0 + pl;
    int s = 0, base = 0;
    while (base + s + 1 <= p) { base += s + 1; ++s; }
    int jj = p - base;

    __shared__ float Wl[64*64];
    int tid = threadIdx.x;
    const float4* wsrc = (const float4*)(wcomb + ((size_t)s*768 + jj*64)*64);
    for (int i = tid; i < 1024; i += 256) ((float4*)Wl)[i] = wsrc[i];
    __syncthreads();

    int c = tid & 63, rl = tid >> 6;
    const _Float16* ob = ocat + (size_t)pl*PLSTR;
    #pragma unroll
    for (int i = 0; i < 4; ++i) {
        int r = rt*16 + i*4 + rl;
        int b = r / NN, n = r % NN;
        const _Float16* orow = ob + ((size_t)b*HEADS*NN + n)*8;
        float a = 0.f;
        #pragma unroll
        for (int h = 0; h < 8; ++h) {
            f16x8 v = *(const f16x8*)(orow + (size_t)h*NN*8);
            a += (float)v[0]*Wl[(h*8+0)*64+c] + (float)v[1]*Wl[(h*8+1)*64+c]
               + (float)v[2]*Wl[(h*8+2)*64+c] + (float)v[3]*Wl[(h*8+3)*64+c]
               + (float)v[4]*Wl[(h*8+4)*64+c] + (float)v[5]*Wl[(h*8+5)*64+c]
               + (float)v[6]*Wl[(h*8+6)*64+c] + (float)v[7]*Wl[(h*8+7)*64+c];
        }
        atomicAdd(&y[((size_t)(b*TS + s)*NN + n)*64 + c], a);
    }
}

// ---------------- K8: finalize fc BN stats ----------------
__global__ void fc_stats(const float* __restrict__ fsum, const float* __restrict__ fsumsq,
                         const float* __restrict__ g, const float* __restrict__ be,
                         float* __restrict__ fsc, float* __restrict__ fsh)
{
    int c = threadIdx.x;
    if (c >= 64) return;
    float mean = fsum[c] * (1.0f / ROWS_FC);
    float var  = fsumsq[c] * (1.0f / ROWS_FC) - mean*mean;
    float sc = g[c] * rsqrtf(var + EPS_);
    fsc[c] = sc;
    fsh[c] = be[c] - mean * sc;
}

// ---------------- K9: final BN+ReLU in place on d_out ----------------
__global__ __launch_bounds__(256) void bn_out(
    float* __restrict__ out, const float* __restrict__ fsc, const float* __restrict__ fsh)
{
    size_t idx = (size_t)blockIdx.x * 256 + threadIdx.x;
    if (idx >= TOT) return;
    int c = (int)(idx & 63);
    out[idx] = fmaxf(out[idx] * fsc[c] + fsh[c], 0.0f);
}

extern "C" void kernel_launch(void* const* d_in, const int* in_sizes, int n_in,
                              void* d_out, int out_size, void* d_ws, size_t ws_size,
                              hipStream_t stream)
{
    const float* X     = (const float*)d_in[0];
    const float* STE   = (const float*)d_in[1];
    const float* Wqkv  = (const float*)d_in[2];
    const float* bqkv  = (const float*)d_in[3];
    const float* gqkv  = (const float*)d_in[4];
    const float* beqkv = (const float*)d_in[5];
    const float* lin_w = (const float*)d_in[6];
    const float* lin_b = (const float*)d_in[7];
    const float* Wfc   = (const float*)d_in[8];
    const float* bfc   = (const float*)d_in[9];
    const float* gfc   = (const float*)d_in[10];
    const float* befc  = (const float*)d_in[11];

    // ws layout (f32 units):
    // [qkvh: TOT/2][st: 4096][wcomb: 12*768*64][bcomb: 768][ocat(f16): CHUNK*PLSTR/2]
    float* ws    = (float*)d_ws;
    _Float16* qkvh = (_Float16*)ws;
    float* st    = ws + (size_t)TOT/2;
    float* wcomb = st + 4096;
    float* bcomb = wcomb + (size_t)TS*768*64;
    _Float16* ocat = (_Float16*)(bcomb + 768);
    float* Y     = (float*)ocat;
    float* y     = (float*)d_out;          // y accumulates in d_out; BN in place

    float* qsum   = st;            // 768
    float* qsumsq = st + 768;      // 768
    float* fsum   = st + 1536;     // 64
    float* fsumsq = st + 1600;     // 64  -> first 1664 floats zeroed each call
    float* qsc    = st + 1664;     // 768
    float* qsh    = st + 2432;     // 768
    float* fsc    = st + 3200;     // 64
    float* fsh    = st + 3264;     // 64

    hipMemsetAsync(st, 0, 1664 * sizeof(float), stream);

    qkv_gemm<<<dim3(BN/QROWS, TS), 256, 0, stream>>>(X, STE, Wqkv, bqkv, Y, qsum, qsumsq);
    qkv_stats<<<3, 256, 0, stream>>>(qsum, qsumsq, gqkv, beqkv, qsc, qsh);
    bn_relayout_h<<<TOT/256, 256, 0, stream>>>(Y, qsc, qsh, qkvh);
    wcomb_k<<<dim3(48, TS), 256, 0, stream>>>(lin_w, Wfc, wcomb);
    bcomb_k<<<3, 256, 0, stream>>>(lin_b, Wfc, bfc, bcomb);
    y_init<<<TOT/256, 256, 0, stream>>>(y, bcomb);

    for (int ch = 0; ch < 2; ++ch) {
        int p0 = ch * CHUNK;
        attn_ocat<<<dim3(CHUNK, BB, HEADS), 256, 0, stream>>>(qkvh, ocat, p0);
        y_accum<<<dim3(NN, CHUNK), 256, 0, stream>>>(ocat, wcomb, y, p0);
    }

    col_reduce<<<dim3(96, 1), 256, 0, stream>>>(y, fsum, fsumsq, ROWS_FC, ROWS_FC/96);
    fc_stats<<<1, 64, 0, stream>>>(fsum, fsumsq, gfc, befc, fsc, fsh);
    bn_out<<<TOT/256, 256, 0, stream>>>(y, fsc, fsh);
}

// Round 22
// 441.958 us; speedup vs baseline: 1.4500x; 1.0423x over previous
//
#include <hip/hip_runtime.h>
#include <math.h>

#define TS 12
#define HEADS 8
#define DH 8
#define DD 64
#define BB 16
#define NN 325
#define BN (BB*NN)               // 5200
#define TOT (TS*BN*DD)           // 3,993,600
#define ROWS_FC (BB*TS*NN)       // 62,400
#define NPAD 336                 // 21 tiles of 16
#define NT 21
#define QROWS 80                 // rows per qkv_gemm block
#define PLSTR (BB*HEADS*NN*8)    // ocat pair stride (f16 elems)
constexpr float EPS_ = 1e-5f;
constexpr float SCALE_ = 0.35355339059327373f;   // 1/sqrt(8)
constexpr float LOG2E_ = 1.4426950408889634f;

typedef _Float16 f16x4 __attribute__((ext_vector_type(4)));
typedef _Float16 f16x2 __attribute__((ext_vector_type(2)));
typedef _Float16 f16x8 __attribute__((ext_vector_type(8)));
typedef float    f32x4 __attribute__((ext_vector_type(4)));

// ---------------- K1: QKV GEMM (80 rows/block) + fused BN-stat partials ----------------
__global__ __launch_bounds__(256, 2) void qkv_gemm(
    const float* __restrict__ X, const float* __restrict__ STE,
    const float* __restrict__ Wqkv, const float* __restrict__ bqkv,
    float* __restrict__ Y, float* __restrict__ qsum, float* __restrict__ qsumsq)
{
    __shared__ float Wl[128*64];        // 32 KB
    __shared__ float Xl[QROWS][132];    // 41.25 KB (reused as stat scratch)
    int t = blockIdx.y;
    int tid = threadIdx.x;
    int r0 = blockIdx.x * QROWS;
    for (int i = tid; i < 2048; i += 256)
        ((float4*)Wl)[i] = ((const float4*)Wqkv)[i];
    for (int i = tid; i < QROWS*32; i += 256) {
        int row = i >> 5, q = i & 31;
        int r = r0 + row;
        int b = r / NN, n = r % NN;
        size_t src = (((size_t)b*TS + t)*NN + n)*DD;
        float4 v = (q < 16) ? ((const float4*)(X + src))[q]
                            : ((const float4*)(STE + src))[q-16];
        *(float4*)&Xl[row][q*4] = v;
    }
    __syncthreads();
    int cg = tid & 15, rg = tid >> 4;
    int c0 = cg*4;
    float4 a[5] = {};
    #pragma unroll 4
    for (int k4 = 0; k4 < 32; ++k4) {
        float4 w0 = *(const float4*)&Wl[(4*k4+0)*64 + c0];
        float4 w1 = *(const float4*)&Wl[(4*k4+1)*64 + c0];
        float4 w2 = *(const float4*)&Wl[(4*k4+2)*64 + c0];
        float4 w3 = *(const float4*)&Wl[(4*k4+3)*64 + c0];
        #pragma unroll
        for (int i = 0; i < 5; ++i) {
            float4 xv = *(const float4*)&Xl[rg*5 + i][k4*4];
            a[i].x += xv.x*w0.x + xv.y*w1.x + xv.z*w2.x + xv.w*w3.x;
            a[i].y += xv.x*w0.y + xv.y*w1.y + xv.z*w2.y + xv.w*w3.y;
            a[i].z += xv.x*w0.z + xv.y*w1.z + xv.z*w2.z + xv.w*w3.z;
            a[i].w += xv.x*w0.w + xv.y*w1.w + xv.z*w2.w + xv.w*w3.w;
        }
    }
    float4 bq = *(const float4*)(bqkv + c0);
    float4 ps = make_float4(0.f,0.f,0.f,0.f), pq = ps;
    #pragma unroll
    for (int i = 0; i < 5; ++i) {
        int r = r0 + rg*5 + i;
        float4 o;
        o.x = a[i].x + bq.x; o.y = a[i].y + bq.y;
        o.z = a[i].z + bq.z; o.w = a[i].w + bq.w;
        *(float4*)&Y[((size_t)t*BN + r)*64 + c0] = o;
        ps.x += o.x; ps.y += o.y; ps.z += o.z; ps.w += o.w;
        pq.x += o.x*o.x; pq.y += o.y*o.y; pq.z += o.z*o.z; pq.w += o.w*o.w;
    }
    float* red = (float*)Xl;
    __syncthreads();
    *(float4*)&red[rg*64 + c0] = ps;
    *(float4*)&red[1024 + rg*64 + c0] = pq;
    __syncthreads();
    if (tid < 64) {
        float s = 0.f, q = 0.f;
        #pragma unroll
        for (int r = 0; r < 16; ++r) { s += red[r*64 + tid]; q += red[1024 + r*64 + tid]; }
        atomicAdd(&qsum[t*64 + tid], s);
        atomicAdd(&qsumsq[t*64 + tid], q);
    }
}

// ---------------- K2: column reduce (sum, sumsq) over [t][R][64] ----------------
__global__ __launch_bounds__(256) void col_reduce(
    const float* __restrict__ src, float* __restrict__ osum, float* __restrict__ osumsq,
    int R, int chunkrows)
{
    __shared__ float red[256];
    int t = blockIdx.y;
    int tid = threadIdx.x;
    int c = tid & 63, rl = tid >> 6;
    int r0 = blockIdx.x * chunkrows;
    int r1 = r0 + chunkrows;
    float s = 0.f, s2 = 0.f;
    for (int r = r0 + rl; r < r1; r += 4) {
        float v = src[((size_t)t*R + r)*64 + c];
        s += v; s2 += v*v;
    }
    red[tid] = s; __syncthreads();
    if (tid < 64) atomicAdd(&osum[t*64 + tid], red[tid] + red[tid+64] + red[tid+128] + red[tid+192]);
    __syncthreads();
    red[tid] = s2; __syncthreads();
    if (tid < 64) atomicAdd(&osumsq[t*64 + tid], red[tid] + red[tid+64] + red[tid+128] + red[tid+192]);
}

// ---------------- K3: finalize QKV BN stats ----------------
__global__ void qkv_stats(const float* __restrict__ qsum, const float* __restrict__ qsumsq,
                          const float* __restrict__ g, const float* __restrict__ be,
                          float* __restrict__ qsc, float* __restrict__ qsh)
{
    int i = blockIdx.x * blockDim.x + threadIdx.x;
    if (i >= TS*64) return;
    int c = i & 63;
    float mean = qsum[i] * (1.0f / BN);
    float var  = qsumsq[i] * (1.0f / BN) - mean*mean;
    float sc = g[c] * rsqrtf(var + EPS_);
    qsc[i] = sc;
    qsh[i] = be[c] - mean * sc;
}

// ---------------- K4: BN+ReLU + relayout to f16 [t][b][h][n][8] ----------------
__global__ __launch_bounds__(256) void bn_relayout_h(
    const float* __restrict__ Y, const float* __restrict__ qsc, const float* __restrict__ qsh,
    _Float16* __restrict__ qkvh)
{
    size_t idx = (size_t)blockIdx.x * 256 + threadIdx.x;
    if (idx >= TOT) return;
    int c = (int)(idx & 63);
    size_t tr = idx >> 6;
    int t = (int)(tr / BN);
    int r = (int)(tr % BN);
    float v = fmaxf(Y[idx] * qsc[t*64 + c] + qsh[t*64 + c], 0.0f);
    int b = r / NN, n = r % NN, h = c >> 3, d = c & 7;
    qkvh[((((size_t)t*BB + b)*HEADS + h)*NN + n)*DH + d] = (_Float16)v;
}

// ---------------- K4b: combined weights Wcomb[s] = lin_w[s] @ W_fc ----------------
__global__ __launch_bounds__(256) void wcomb_k(
    const float* __restrict__ lin_w, const float* __restrict__ Wfc,
    float* __restrict__ wcomb)
{
    __shared__ float Wl[64*64];
    int s = blockIdx.y, kt = blockIdx.x;
    int tid = threadIdx.x;
    int c = tid & 63, rl = tid >> 6;
    for (int i = tid; i < 1024; i += 256)
        ((float4*)Wl)[i] = ((const float4*)Wfc)[i];
    __syncthreads();
    #pragma unroll
    for (int i = 0; i < 4; ++i) {
        int k = kt*16 + rl*4 + i;
        const float* lw = lin_w + ((size_t)s*768 + k)*64;
        float a = 0.f;
        #pragma unroll
        for (int m4 = 0; m4 < 16; ++m4) {
            float4 lv = *(const float4*)(lw + m4*4);
            a += lv.x*Wl[(4*m4+0)*64+c] + lv.y*Wl[(4*m4+1)*64+c]
               + lv.z*Wl[(4*m4+2)*64+c] + lv.w*Wl[(4*m4+3)*64+c];
        }
        wcomb[((size_t)s*768 + k)*64 + c] = a;
    }
}

// ---------------- K4c: bcomb[s] = lin_b[s] @ W_fc + b_fc ----------------
__global__ void bcomb_k(const float* __restrict__ lin_b, const float* __restrict__ Wfc,
                        const float* __restrict__ bfc, float* __restrict__ bcomb)
{
    int i = blockIdx.x * 256 + threadIdx.x;
    if (i >= TS*64) return;
    int s = i >> 6, c = i & 63;
    float a = bfc[c];
    for (int m = 0; m < 64; ++m) a += lin_b[s*64 + m] * Wfc[m*64 + c];
    bcomb[i] = a;
}

// ---------------- K4d: y_init — seed y with bcomb[s] ----------------
__global__ __launch_bounds__(256) void y_init(
    float* __restrict__ y, const float* __restrict__ bcomb)
{
    size_t idx = (size_t)blockIdx.x * 256 + threadIdx.x;
    if (idx >= TOT) return;
    int c = (int)(idx & 63);
    size_t row = idx >> 6;
    int s = (int)((row / NN) % TS);
    y[idx] = bcomb[s*64 + c];
}

// ---------------- K5: MFMA attention, 3-group online softmax, f16 ocat ----------------
__global__ __launch_bounds__(256, 4) void attn_ocat(
    const _Float16* __restrict__ qkvh, _Float16* __restrict__ ocat, int p0)
{
    int pl = blockIdx.x, b = blockIdx.y, h = blockIdx.z;
    int p = p0 + pl;
    int s = 0, base = 0;
    while (base + s + 1 <= p) { base += s + 1; ++s; }
    int j = p - base;

    __shared__ _Float16 Kl[NPAD*8];          // [m][k], rows m>=325 zero
    __shared__ _Float16 VT[16][NPAD+8];      // [d][m], d 9..15 zero, d=8 ones

    int tid  = threadIdx.x;
    int lane = tid & 63, wv = tid >> 6;
    int lq = lane >> 4, lr = lane & 15;

    for (int i = tid; i < (NPAD*8)/2; i += 256) ((unsigned*)Kl)[i] = 0u;
    for (int i = tid; i < (16*(NPAD+8))/2; i += 256) ((unsigned*)(&VT[0][0]))[i] = 0u;
    __syncthreads();
    const _Float16* kvsrc = qkvh + (((size_t)j*BB + b)*HEADS + h)*(NN*DH);
    for (int i = tid; i < (NN*DH)/2; i += 256) ((unsigned*)Kl)[i] = ((const unsigned*)kvsrc)[i];
    for (int i = tid; i < NN*DH; i += 256) { int m = i >> 3, d = i & 7; VT[d][m] = kvsrc[i]; }
    for (int i = tid; i < NPAD; i += 256) VT[8][i] = (_Float16)1.0f;   // den row
    __syncthreads();

    const _Float16* qh = qkvh + (((size_t)s*BB + b)*HEADS + h)*(NN*DH);
    _Float16* obase = ocat + (((size_t)(pl*BB + b)*HEADS + h)*NN)*8;

    for (int st = wv; st < NT; st += 4) {
        int n0 = st * 16;
        f16x4 qf = {0,0,0,0};
        int nq = n0 + lr;
        if (lq < 2 && nq < NN) qf = *(const f16x4*)(qh + nq*DH + lq*4);
        qf *= (_Float16)(SCALE_ * LOG2E_);   // log2-domain scores

        f32x4 ot = {0.f, 0.f, 0.f, 0.f};
        float mx = 0.f;                      // S >= 0 always (ReLU'd Q,K)
        #pragma unroll
        for (int g = 0; g < 3; ++g) {
            const int mt0 = g * 7;
            const int mt1 = mt0 + 7;
            f32x4 S[7];
            float gmx = 0.f;
            #pragma unroll
            for (int mt = mt0; mt < mt1; ++mt) {
                f16x4 kf = {0,0,0,0};
                if (lq < 2) kf = *(const f16x4*)(&Kl[(mt*16 + lr)*8 + lq*4]);
                S[mt-mt0] = __builtin_amdgcn_mfma_f32_16x16x16f16(kf, qf, (f32x4){0.f,0.f,0.f,0.f}, 0, 0, 0);
                gmx = fmaxf(gmx, fmaxf(fmaxf(S[mt-mt0][0], S[mt-mt0][1]),
                                       fmaxf(S[mt-mt0][2], S[mt-mt0][3])));
            }
            gmx = fmaxf(gmx, __shfl_xor(gmx, 16));
            gmx = fmaxf(gmx, __shfl_xor(gmx, 32));
            float nmx = fmaxf(mx, gmx);
            ot *= __builtin_amdgcn_exp2f(mx - nmx);   // rescale prior acc (den row too)
            mx = nmx;
            #pragma unroll
            for (int mt = mt0; mt < mt1; ++mt) {
                float e0 = __builtin_amdgcn_exp2f(S[mt-mt0][0] - mx);
                float e1 = __builtin_amdgcn_exp2f(S[mt-mt0][1] - mx);
                float e2 = __builtin_amdgcn_exp2f(S[mt-mt0][2] - mx);
                float e3 = __builtin_amdgcn_exp2f(S[mt-mt0][3] - mx);
                if (mt == NT-1) {                 // only tile 20 has pad rows
                    if (lq*4 + 0 >= 5) e0 = 0.f;
                    if (lq*4 + 1 >= 5) e1 = 0.f;
                    if (lq*4 + 2 >= 5) e2 = 0.f;
                    if (lq*4 + 3 >= 5) e3 = 0.f;
                }
                f16x2 plo = __builtin_bit_cast(f16x2, __builtin_amdgcn_cvt_pkrtz(e0, e1));
                f16x2 phi = __builtin_bit_cast(f16x2, __builtin_amdgcn_cvt_pkrtz(e2, e3));
                f16x4 pf = {plo.x, plo.y, phi.x, phi.y};
                f16x4 vf = *(const f16x4*)(&VT[lr][mt*16 + lq*4]);
                ot = __builtin_amdgcn_mfma_f32_16x16x16f16(vf, pf, ot, 0, 0, 0);
            }
        }
        float den = __shfl(ot[0], 32 + lr);   // C row 8 lives in lanes 32..47
        float inv = __builtin_amdgcn_rcpf(den);

        if (lq < 2 && nq < NN) {
            f16x2 a01 = __builtin_bit_cast(f16x2, __builtin_amdgcn_cvt_pkrtz(ot[0]*inv, ot[1]*inv));
            f16x2 a23 = __builtin_bit_cast(f16x2, __builtin_amdgcn_cvt_pkrtz(ot[2]*inv, ot[3]*inv));
            f16x4 o4 = {a01.x, a01.y, a23.x, a23.y};
            *(f16x4*)(obase + (size_t)nq*8 + lq*4) = o4;
        }
    }
}

// ---------------- K6: y_accum — one block per (rowtile, pair), rank-64 update ----------------
__global__ __launch_bounds__(256) void y_accum(
    const _Float16* __restrict__ ocat, const float* __restrict__ wcomb,
    float* y, int p0)
{
    int rt = blockIdx.x, pl = blockIdx.y;
    int p = p0 + pl;
    int s = 0, base = 0;
    while (base + s + 1 <= p) { base += s + 1; ++s; }
    int jj = p - base;

    __shared__ float Wl[64*64];
    int tid = threadIdx.x;
    const float4* wsrc = (const float4*)(wcomb + ((size_t)s*768 + jj*64)*64);
    for (int i = tid; i < 1024; i += 256) ((float4*)Wl)[i] = wsrc[i];
    __syncthreads();

    int c = tid & 63, rl = tid >> 6;
    const _Float16* ob = ocat + (size_t)pl*PLSTR;
    #pragma unroll
    for (int i = 0; i < 4; ++i) {
        int r = rt*16 + i*4 + rl;
        int b = r / NN, n = r % NN;
        const _Float16* orow = ob + ((size_t)b*HEADS*NN + n)*8;
        float a = 0.f;
        #pragma unroll
        for (int h = 0; h < 8; ++h) {
            f16x8 v = *(const f16x8*)(orow + (size_t)h*NN*8);
            a += (float)v[0]*Wl[(h*8+0)*64+c] + (float)v[1]*Wl[(h*8+1)*64+c]
               + (float)v[2]*Wl[(h*8+2)*64+c] + (float)v[3]*Wl[(h*8+3)*64+c]
               + (float)v[4]*Wl[(h*8+4)*64+c] + (float)v[5]*Wl[(h*8+5)*64+c]
               + (float)v[6]*Wl[(h*8+6)*64+c] + (float)v[7]*Wl[(h*8+7)*64+c];
        }
        atomicAdd(&y[((size_t)(b*TS + s)*NN + n)*64 + c], a);
    }
}

// ---------------- K8: finalize fc BN stats ----------------
__global__ void fc_stats(const float* __restrict__ fsum, const float* __restrict__ fsumsq,
                         const float* __restrict__ g, const float* __restrict__ be,
                         float* __restrict__ fsc, float* __restrict__ fsh)
{
    int c = threadIdx.x;
    if (c >= 64) return;
    float mean = fsum[c] * (1.0f / ROWS_FC);
    float var  = fsumsq[c] * (1.0f / ROWS_FC) - mean*mean;
    float sc = g[c] * rsqrtf(var + EPS_);
    fsc[c] = sc;
    fsh[c] = be[c] - mean * sc;
}

// ---------------- K9: final BN+ReLU in place on d_out ----------------
__global__ __launch_bounds__(256) void bn_out(
    float* __restrict__ out, const float* __restrict__ fsc, const float* __restrict__ fsh)
{
    size_t idx = (size_t)blockIdx.x * 256 + threadIdx.x;
    if (idx >= TOT) return;
    int c = (int)(idx & 63);
    out[idx] = fmaxf(out[idx] * fsc[c] + fsh[c], 0.0f);
}

extern "C" void kernel_launch(void* const* d_in, const int* in_sizes, int n_in,
                              void* d_out, int out_size, void* d_ws, size_t ws_size,
                              hipStream_t stream)
{
    const float* X     = (const float*)d_in[0];
    const float* STE   = (const float*)d_in[1];
    const float* Wqkv  = (const float*)d_in[2];
    const float* bqkv  = (const float*)d_in[3];
    const float* gqkv  = (const float*)d_in[4];
    const float* beqkv = (const float*)d_in[5];
    const float* lin_w = (const float*)d_in[6];
    const float* lin_b = (const float*)d_in[7];
    const float* Wfc   = (const float*)d_in[8];
    const float* bfc   = (const float*)d_in[9];
    const float* gfc   = (const float*)d_in[10];
    const float* befc  = (const float*)d_in[11];

    // ws layout (f32 units):
    // [qkvh: TOT/2][st: 4096][wcomb: 12*768*64][bcomb: 768][ocat(f16): chunk*PLSTR/2]
    float* ws    = (float*)d_ws;
    _Float16* qkvh = (_Float16*)ws;
    float* st    = ws + (size_t)TOT/2;
    float* wcomb = st + 4096;
    float* bcomb = wcomb + (size_t)TS*768*64;
    _Float16* ocat = (_Float16*)(bcomb + 768);
    float* Y     = (float*)ocat;
    float* y     = (float*)d_out;          // y accumulates in d_out; BN in place

    float* qsum   = st;            // 768
    float* qsumsq = st + 768;      // 768
    float* fsum   = st + 1536;     // 64
    float* fsumsq = st + 1600;     // 64  -> first 1664 floats zeroed each call
    float* qsc    = st + 1664;     // 768
    float* qsh    = st + 2432;     // 768
    float* fsc    = st + 3200;     // 64
    float* fsh    = st + 3264;     // 64

    // R22: single-pass (chunk=78) if ws allows, else the proven 2-pass (39).
    // Deterministic in ws_size; removes 2 serialization boundaries.
    size_t fixed_f32 = (size_t)TOT/2 + 4096 + (size_t)TS*768*64 + 768;
    size_t avail_f16 = (ws_size/4 > fixed_f32) ? (ws_size/4 - fixed_f32)*2 : 0;
    int chunk = (avail_f16 >= (size_t)78*PLSTR) ? 78 : 39;

    hipMemsetAsync(st, 0, 1664 * sizeof(float), stream);

    qkv_gemm<<<dim3(BN/QROWS, TS), 256, 0, stream>>>(X, STE, Wqkv, bqkv, Y, qsum, qsumsq);
    qkv_stats<<<3, 256, 0, stream>>>(qsum, qsumsq, gqkv, beqkv, qsc, qsh);
    bn_relayout_h<<<TOT/256, 256, 0, stream>>>(Y, qsc, qsh, qkvh);
    wcomb_k<<<dim3(48, TS), 256, 0, stream>>>(lin_w, Wfc, wcomb);
    bcomb_k<<<3, 256, 0, stream>>>(lin_b, Wfc, bfc, bcomb);
    y_init<<<TOT/256, 256, 0, stream>>>(y, bcomb);

    for (int p0 = 0; p0 < 78; p0 += chunk) {
        attn_ocat<<<dim3(chunk, BB, HEADS), 256, 0, stream>>>(qkvh, ocat, p0);
        y_accum<<<dim3(NN, chunk), 256, 0, stream>>>(ocat, wcomb, y, p0);
    }

    col_reduce<<<dim3(96, 1), 256, 0, stream>>>(y, fsum, fsumsq, ROWS_FC, ROWS_FC/96);
    fc_stats<<<1, 64, 0, stream>>>(fsum, fsumsq, gfc, befc, fsc, fsh);
    bn_out<<<TOT/256, 256, 0, stream>>>(y, fsc, fsh);
}